// Round 4
// baseline (452.562 us; speedup 1.0000x reference)
//
#include <hip/hip_runtime.h>
#include <stdint.h>

#pragma clang fp contract(off)

typedef _Float16 f16x8 __attribute__((ext_vector_type(8)));
typedef float f32x4 __attribute__((ext_vector_type(4)));
typedef unsigned short u16;
typedef u16 u16x8 __attribute__((ext_vector_type(8)));

#define T_   4
#define B_   16
#define C_   512
#define HID_ 2048
#define NPIX 256
#define Z_   64            // T_*B_

// ---------------- workspace layout (bytes) ----------------
constexpr size_t OFF_SC_Q    = 0;         // each sc slot 8KB
constexpr size_t OFF_SC_K    = 8192;
constexpr size_t OFF_SC_V    = 16384;
constexpr size_t OFF_SC_PROJ = 24576;
constexpr size_t OFF_SC_FC1  = 32768;
constexpr size_t OFF_SC_FC2  = 40960;
constexpr size_t OFF_PRESUM  = 65536;     // 64*512 f32 = 128KB
constexpr size_t OFF_MASK    = 196608;    // 64*512 u16 = 64KB
constexpr size_t OFF_W       = 262144;
constexpr size_t WSZ_S       = 524288;    // 512*512*2
constexpr size_t WSZ_QKV     = 1572864;   // 1536*512*2
constexpr size_t WSZ_L       = 2097152;   // 2048*512*2
constexpr size_t OFF_QKVHI = OFF_W;
constexpr size_t OFF_QKVLO = OFF_QKVHI + WSZ_QKV;
constexpr size_t OFF_PHI   = OFF_QKVLO + WSZ_QKV;
constexpr size_t OFF_PLO   = OFF_PHI + WSZ_S;
constexpr size_t OFF_F1HI  = OFF_PLO + WSZ_S;
constexpr size_t OFF_F1LO  = OFF_F1HI + WSZ_L;
constexpr size_t OFF_F2HI  = OFF_F1LO + WSZ_L;
constexpr size_t OFF_F2LO  = OFF_F2HI + WSZ_L;
constexpr size_t OFF_SPK   = OFF_F2LO + WSZ_L;
constexpr size_t SPKB      = 16777216;                 // 64*256*512*2
constexpr size_t OFF_SPK_A   = OFF_SPK;                // xs -> att
constexpr size_t OFF_SPK_QKV = OFF_SPK + SPKB;         // [z][n][1536] (3*SPKB)
constexpr size_t OFF_SPK_E   = OFF_SPK + 4*SPKB;       // h1
constexpr size_t OFF_H2      = OFF_SPK + 5*SPKB;       // h2 (4*SPKB)

// ---------------- prep: BN scale ----------------
__global__ void prep_sc_kernel(const float* __restrict__ bn, float* __restrict__ sc, int Cn) {
    int c = blockIdx.x * blockDim.x + threadIdx.x;
    if (c < Cn) sc[c] = bn[c] / sqrtf(bn[3 * Cn + c] + 1e-5f);
}

// ---------------- prep: f16 2-split of fp32 weights (lo pre-scaled by 2^11) ----------------
__global__ void prep_split_kernel(const float* __restrict__ W, u16* __restrict__ hi,
                                  u16* __restrict__ lo, int n) {
    int i = blockIdx.x * 256 + threadIdx.x;
    if (i >= n) return;
    float w = W[i];
    _Float16 h = (_Float16)w;
    float d = w - (float)h;               // exact
    _Float16 l = (_Float16)(d * 2048.0f); // keep lo in f16 normal range
    hi[i] = *(const u16*)&h;
    lo[i] = *(const u16*)&l;
}

// ---------------- LIF + transpose: y[T,B,Cf,N] f32 -> spk[z][n][c] f16 ----------------
__global__ __launch_bounds__(256) void lif_transpose_kernel(
        const float* __restrict__ y, u16* __restrict__ spk, int Cf) {
    __shared__ __align__(16) u16 tile[256 * 72];   // [t*64+nn][72]
    int b  = blockIdx.z;
    int c0 = blockIdx.y * 64;
    int n0 = blockIdx.x * 64;
    int tid = threadIdx.x;
    int nn = tid & 63;
    int cg = tid >> 6;
    size_t tstride = (size_t)B_ * Cf * NPIX;
    for (int e = 0; e < 16; ++e) {
        int ci = cg * 16 + e;
        size_t base = ((size_t)b * Cf + c0 + ci) * NPIX + n0 + nn;
        float v = 0.0f;
        #pragma unroll
        for (int t = 0; t < T_; ++t) {
            float x = y[base + (size_t)t * tstride];
            v = v + (x - v) * 0.5f;
            u16 s = 0;
            if (v >= 1.0f) { s = 0x3C00; v = 0.0f; }
            tile[(t * 64 + nn) * 72 + ci] = s;
        }
    }
    __syncthreads();
    int t = tid >> 6, n2 = tid & 63;
    const u16* srow = &tile[(t * 64 + n2) * 72];
    u16* drow = spk + ((size_t)((t * B_ + b) * NPIX) + n0 + n2) * Cf + c0;
    #pragma unroll
    for (int kk = 0; kk < 8; ++kk)
        *(u16x8*)(drow + kk * 8) = *(const u16x8*)(srow + kk * 8);
}

// ---------------- kv presum from fused qkv spikes: counts of (k & v) over n ----------------
__global__ void kv_presum_kernel(const u16* __restrict__ qkv, float* __restrict__ presum) {
    int z = blockIdx.x;
    int tid = threadIdx.x;
    const uint* base = (const uint*)(qkv + (size_t)z * NPIX * 1536);
    int s0 = 0, s1 = 0;
    for (int n = 0; n < NPIX; ++n) {
        uint a = base[n * 768 + 256 + tid];   // k cols 512..1023
        uint b = base[n * 768 + 512 + tid];   // v cols 1024..1535
        uint c = a & b;
        s0 += (c >> 10) & 1;
        s1 += (c >> 26) & 1;
    }
    presum[z * C_ + 2 * tid]     = (float)s0;
    presum[z * C_ + 2 * tid + 1] = (float)s1;
}

// ---------------- kv LIF (vth=0.5) -> mask u16 ----------------
__global__ void kv_lif_mask_kernel(const float* __restrict__ presum, u16* __restrict__ mask) {
    int i = blockIdx.x * 256 + threadIdx.x;   // 8192 = B_*C_
    int b = i >> 9, c = i & (C_ - 1);
    float v = 0.0f;
    #pragma unroll
    for (int t = 0; t < T_; ++t) {
        float x = presum[((t * B_ + b) << 9) + c];
        v = v + (x - v) * 0.5f;
        u16 m = 0;
        if (v >= 0.5f) { m = 0xFFFF; v = 0.0f; }
        mask[((t * B_ + b) << 9) + c] = m;
    }
}

// ---------------- att = q & mask (q strided 1536, out compact 512) ----------------
__global__ void att_apply_kernel(const u16* __restrict__ qkv, const u16* __restrict__ mask,
                                 u16* __restrict__ att) {
    size_t i = (size_t)blockIdx.x * 256 + threadIdx.x;  // over 64*256*128 uint2-groups
    int z   = (int)(i >> 15);
    int rem = (int)(i & 32767);
    int n   = rem >> 7;
    int c4  = rem & 127;
    uint2 qv = ((const uint2*)qkv)[((size_t)z * NPIX + n) * 384 + c4];  // q at cols 0..511
    uint2 mv = ((const uint2*)(mask + (size_t)z * C_))[c4];
    uint2 r;
    r.x = qv.x & mv.x;
    r.y = qv.y & mv.y;
    ((uint2*)att)[i] = r;
}

// ---------------- vh output: out2[(z*8+h)][n][ch] = v[z][n][1024+h*64+ch] as f32 ----------------
__global__ void vh_write_kernel(const u16* __restrict__ qkv, float* __restrict__ out2) {
    int slab = blockIdx.x;           // z*8+h
    int z = slab >> 3, h = slab & 7;
    int tid = threadIdx.x;
    int n = tid >> 2, cg = tid & 3;
    for (int it = 0; it < 4; ++it) {
        int nn = n + it * 64;
        const u16* src = qkv + ((size_t)z * NPIX + nn) * 1536 + 1024 + h * 64 + cg * 16;
        float* dst = out2 + ((size_t)slab * NPIX + nn) * 64 + cg * 16;
        #pragma unroll
        for (int j = 0; j < 16; ++j) dst[j] = src[j] ? 1.0f : 0.0f;
    }
}

// ---------------- fused MFMA GEMM, dbuf BK=32, 64o x 64p x 4z, BN/LIF fused ----------------
// Sections: if bnp2/bnp3 non-null, o in [512,1024) uses bnp2/sc2, [1024,1536) uses bnp3/sc3
// (BN tables each sized Cn). mode 0: spikes only; 1: f32 y(+res) AND spikes; 2: f32(+res) only.
__global__ __launch_bounds__(256, 2) void gemm_fused_kernel(
        const u16* __restrict__ S,     // [64][256][Cin] f16 spikes
        const u16* __restrict__ Whi,   // [Cout][Cin]
        const u16* __restrict__ Wlo,
        const float* __restrict__ bias,
        const float* __restrict__ bnp,  const float* __restrict__ sc,
        const float* __restrict__ bnp2, const float* __restrict__ sc2,
        const float* __restrict__ bnp3, const float* __restrict__ sc3,
        const float* res,              // [z][Cout][256] or null (may alias yout)
        float* yout,                   // [z][Cout][256] (modes 1,2)
        u16* spkout,                   // [z][n][Cout]   (modes 0,1)
        int Cin, int Cout, int Cn, int mode) {
    __shared__ __align__(16) char lds[49152];   // 2 stages x (Ahi 4K | Alo 4K | B 16K)
    float* ldsf = (float*)lds;
    const int tid  = threadIdx.x;
    const int lane = tid & 63;
    const int w    = tid >> 6;           // wave index = timestep t
    const int r15 = lane & 15, quad = lane >> 4;
    const int b  = blockIdx.z;
    const int o0 = blockIdx.y * 64;
    const int p0 = blockIdx.x * 64;
    const int zt = w * B_ + b;

    f32x4 acc1[4][4], acc2[4][4];
    #pragma unroll
    for (int a = 0; a < 4; ++a)
        #pragma unroll
        for (int c = 0; c < 4; ++c) {
            acc1[a][c] = (f32x4){0.f, 0.f, 0.f, 0.f};
            acc2[a][c] = (f32x4){0.f, 0.f, 0.f, 0.f};
        }

    const int srow = lane >> 2;   // staging row within 16-row group
    const int sj   = lane & 3;    // staging 16B chunk slot

    // stage one BK=32 slab into buffer st
    auto stage = [&](int k0, int st) {
        #pragma unroll
        for (int e = 0; e < 6; ++e) {
            int g = w * 6 + e;              // 0..23
            const u16* src;
            int dstoff;
            if (g < 4) {                    // Ahi: 64 rows
                int m = g * 16 + srow;
                src = Whi + (size_t)(o0 + m) * Cin + k0 + ((sj ^ (m & 3)) << 3);
                dstoff = g * 1024;
            } else if (g < 8) {             // Alo
                int m = (g - 4) * 16 + srow;
                src = Wlo + (size_t)(o0 + m) * Cin + k0 + ((sj ^ (m & 3)) << 3);
                dstoff = 4096 + (g - 4) * 1024;
            } else {                        // B: 256 rows = 4z x 64p
                int r = (g - 8) * 16 + srow;
                int t = r >> 6, p = r & 63;
                src = S + ((size_t)((t * B_ + b) * NPIX + p0 + p)) * Cin + k0
                      + ((sj ^ (r & 3)) << 3);
                dstoff = 8192 + (g - 8) * 1024;
            }
            char* dst = lds + st * 24576 + dstoff;
            __builtin_amdgcn_global_load_lds(
                (const __attribute__((address_space(1))) void*)(uintptr_t)(const void*)src,
                (__attribute__((address_space(3))) void*)(uintptr_t)(void*)dst,
                16, 0, 0);
        }
    };

    const int nIter = Cin >> 5;
    stage(0, 0);
    for (int i = 0; i < nIter; ++i) {
        __syncthreads();                     // drains stage(i); compute(i-1) done
        if (i + 1 < nIter) stage((i + 1) << 5, (i + 1) & 1);
        const char* base = lds + (i & 1) * 24576;
        f16x8 af[4], al[4], bf[4];
        #pragma unroll
        for (int mt = 0; mt < 4; ++mt) {
            int m = mt * 16 + r15;
            int ad = m * 64 + ((quad ^ (m & 3)) << 4);
            af[mt] = *(const f16x8*)(base + ad);
            al[mt] = *(const f16x8*)(base + 4096 + ad);
        }
        #pragma unroll
        for (int nt = 0; nt < 4; ++nt) {
            int p = nt * 16 + r15;
            int ad = p * 64 + ((quad ^ (p & 3)) << 4);
            bf[nt] = *(const f16x8*)(base + 8192 + w * 4096 + ad);
        }
        #pragma unroll
        for (int mt = 0; mt < 4; ++mt)
            #pragma unroll
            for (int nt = 0; nt < 4; ++nt) {
                acc1[mt][nt] = __builtin_amdgcn_mfma_f32_16x16x32_f16(af[mt], bf[nt], acc1[mt][nt], 0, 0, 0);
                acc2[mt][nt] = __builtin_amdgcn_mfma_f32_16x16x32_f16(al[mt], bf[nt], acc2[mt][nt], 0, 0, 0);
            }
    }

    // section-select BN params (qkv fused case)
    const float* bnpS = bnp;
    const float* scS  = sc;
    int ol0 = o0;
    if (bnp3 && o0 >= 1024)      { bnpS = bnp3; scS = sc3; ol0 = o0 - 1024; }
    else if (bnp2 && o0 >= 512)  { bnpS = bnp2; scS = sc2; ol0 = o0 - 512; }

    // combine splits + bias + BN (+res)
    f32x4 yv[4][4];
    const float inv2048 = 1.0f / 2048.0f;
    #pragma unroll
    for (int mt = 0; mt < 4; ++mt) {
        int obl = ol0 + mt * 16 + quad * 4;
        float scv[4], mm[4], bb[4], bv[4];
        #pragma unroll
        for (int r = 0; r < 4; ++r) {
            int o = obl + r;
            scv[r] = scS[o];
            mm[r]  = bnpS[2 * Cn + o];
            bb[r]  = bnpS[Cn + o];
            bv[r]  = bias ? bias[o] : 0.0f;
        }
        #pragma unroll
        for (int nt = 0; nt < 4; ++nt) {
            int p = p0 + nt * 16 + r15;
            #pragma unroll
            for (int r = 0; r < 4; ++r) {
                float y = acc1[mt][nt][r] + acc2[mt][nt][r] * inv2048 + bv[r];
                float val = (y - mm[r]) * scv[r] + bb[r];
                if (mode != 0) {
                    size_t idx = ((size_t)zt * Cout + o0 + mt * 16 + quad * 4 + r) * NPIX + p;
                    val += res[idx];
                }
                yv[mt][nt][r] = val;
            }
        }
    }
    if (mode != 0) {
        #pragma unroll
        for (int mt = 0; mt < 4; ++mt) {
            int ob = o0 + mt * 16 + quad * 4;
            #pragma unroll
            for (int nt = 0; nt < 4; ++nt) {
                int p = p0 + nt * 16 + r15;
                #pragma unroll
                for (int r = 0; r < 4; ++r)
                    yout[((size_t)zt * Cout + ob + r) * NPIX + p] = yv[mt][nt][r];
            }
        }
    }
    if (mode != 2) {
        // LIF across the 4 waves' timesteps via LDS, two 32-pixel passes
        __syncthreads();
        const int og = tid & 7, pi = tid >> 3;    // og: o-group of 8, pi: 0..31
        #pragma unroll
        for (int ph = 0; ph < 2; ++ph) {
            #pragma unroll
            for (int mt = 0; mt < 4; ++mt) {
                int ol = mt * 16 + quad * 4;
                #pragma unroll
                for (int ntl = 0; ntl < 2; ++ntl) {
                    int nt = 2 * ph + ntl;
                    int pl = nt * 16 + r15 - ph * 32;   // 0..31
                    #pragma unroll
                    for (int r = 0; r < 4; ++r)
                        ldsf[w * 2112 + (ol + r) * 33 + pl] = yv[mt][nt][r];
                }
            }
            __syncthreads();
            u16 sp[4][8];
            #pragma unroll
            for (int jj = 0; jj < 8; ++jj) {
                float v = 0.0f;
                #pragma unroll
                for (int t = 0; t < T_; ++t) {
                    float x = ldsf[t * 2112 + (og * 8 + jj) * 33 + pi];
                    v = v + (x - v) * 0.5f;
                    u16 s = 0;
                    if (v >= 1.0f) { s = 0x3C00; v = 0.0f; }
                    sp[t][jj] = s;
                }
            }
            #pragma unroll
            for (int t = 0; t < T_; ++t) {
                u16x8 vv;
                #pragma unroll
                for (int jj = 0; jj < 8; ++jj) vv[jj] = sp[t][jj];
                *(u16x8*)(spkout + ((size_t)((t * B_ + b) * NPIX + p0 + ph * 32 + pi)) * Cout
                          + o0 + og * 8) = vv;
            }
            __syncthreads();
        }
    }
}

extern "C" void kernel_launch(void* const* d_in, const int* in_sizes, int n_in,
                              void* d_out, int out_size, void* d_ws, size_t ws_size,
                              hipStream_t stream) {
    (void)in_sizes; (void)n_in; (void)out_size; (void)ws_size;
    const float* x       = (const float*)d_in[0];
    const float* q_w     = (const float*)d_in[1];
    const float* k_w     = (const float*)d_in[2];
    const float* v_w     = (const float*)d_in[3];
    const float* proj_w  = (const float*)d_in[4];
    const float* proj_b  = (const float*)d_in[5];
    const float* fc1_w   = (const float*)d_in[6];
    const float* fc1_b   = (const float*)d_in[7];
    const float* fc2_w   = (const float*)d_in[8];
    const float* fc2_b   = (const float*)d_in[9];
    const float* q_bn    = (const float*)d_in[10];
    const float* k_bn    = (const float*)d_in[11];
    const float* v_bn    = (const float*)d_in[12];
    const float* proj_bn = (const float*)d_in[13];
    const float* fc1_bn  = (const float*)d_in[14];
    const float* fc2_bn  = (const float*)d_in[15];

    char* ws = (char*)d_ws;
    float* sc_q    = (float*)(ws + OFF_SC_Q);
    float* sc_k    = (float*)(ws + OFF_SC_K);
    float* sc_v    = (float*)(ws + OFF_SC_V);
    float* sc_proj = (float*)(ws + OFF_SC_PROJ);
    float* sc_fc1  = (float*)(ws + OFF_SC_FC1);
    float* sc_fc2  = (float*)(ws + OFF_SC_FC2);
    float* presum  = (float*)(ws + OFF_PRESUM);
    u16*   maskp   = (u16*)(ws + OFF_MASK);
    u16 *qkvhi = (u16*)(ws + OFF_QKVHI), *qkvlo = (u16*)(ws + OFF_QKVLO);
    u16 *phi = (u16*)(ws + OFF_PHI), *plo = (u16*)(ws + OFF_PLO);
    u16 *f1hi = (u16*)(ws + OFF_F1HI), *f1lo = (u16*)(ws + OFF_F1LO);
    u16 *f2hi = (u16*)(ws + OFF_F2HI), *f2lo = (u16*)(ws + OFF_F2LO);
    u16* spkA   = (u16*)(ws + OFF_SPK_A);    // xs -> att
    u16* spkQKV = (u16*)(ws + OFF_SPK_QKV);  // [z][n][1536]
    u16* spkE   = (u16*)(ws + OFF_SPK_E);    // h1
    u16* h2     = (u16*)(ws + OFF_H2);       // h2 (67MB)

    float* out1 = (float*)d_out;
    float* out2 = out1 + 8388608;
    float* x_attn = out1;                 // x_attn lives in out1 until fc2 overwrites in-place

    // BN scales
    prep_sc_kernel<<<2, 256, 0, stream>>>(q_bn,    sc_q,    C_);
    prep_sc_kernel<<<2, 256, 0, stream>>>(k_bn,    sc_k,    C_);
    prep_sc_kernel<<<2, 256, 0, stream>>>(v_bn,    sc_v,    C_);
    prep_sc_kernel<<<2, 256, 0, stream>>>(proj_bn, sc_proj, C_);
    prep_sc_kernel<<<8, 256, 0, stream>>>(fc1_bn,  sc_fc1,  HID_);
    prep_sc_kernel<<<2, 256, 0, stream>>>(fc2_bn,  sc_fc2,  C_);

    // weight splits (q,k,v concatenated into one [1536][512] pair)
    prep_split_kernel<<<1024, 256, 0, stream>>>(q_w,    qkvhi,              qkvlo,              C_ * C_);
    prep_split_kernel<<<1024, 256, 0, stream>>>(k_w,    qkvhi + C_ * C_,    qkvlo + C_ * C_,    C_ * C_);
    prep_split_kernel<<<1024, 256, 0, stream>>>(v_w,    qkvhi + 2 * C_ * C_, qkvlo + 2 * C_ * C_, C_ * C_);
    prep_split_kernel<<<1024, 256, 0, stream>>>(proj_w, phi,  plo,  C_ * C_);
    prep_split_kernel<<<4096, 256, 0, stream>>>(fc1_w,  f1hi, f1lo, HID_ * C_);
    prep_split_kernel<<<4096, 256, 0, stream>>>(fc2_w,  f2hi, f2lo, C_ * HID_);

    dim3 gLT(4, 8, 16);       // lif_transpose on x (Cf=512)
    dim3 gQKV(4, 24, 16);     // fused gemm, Cout=1536
    dim3 gG(4, 8, 16);        // fused gemm, Cout=512
    dim3 gGf1(4, 32, 16);     // fused gemm, Cout=2048

    // shortcut LIF on x -> xs spikes [z][n][c]
    lif_transpose_kernel<<<gLT, 256, 0, stream>>>(x, spkA, C_);

    // q+k+v fused: GEMM+BN+LIF -> spikes [z][n][1536]
    gemm_fused_kernel<<<gQKV, 256, 0, stream>>>(spkA, qkvhi, qkvlo, nullptr,
                                                q_bn, sc_q, k_bn, sc_k, v_bn, sc_v,
                                                nullptr, nullptr, spkQKV, C_, 1536, C_, 0);

    // vh output + kv reduce + talking-heads LIF + att mask
    vh_write_kernel<<<512, 256, 0, stream>>>(spkQKV, out2);
    kv_presum_kernel<<<64, 256, 0, stream>>>(spkQKV, presum);
    kv_lif_mask_kernel<<<32, 256, 0, stream>>>(presum, maskp);
    att_apply_kernel<<<8192, 256, 0, stream>>>(spkQKV, maskp, spkA);   // att into A (xs dead)

    // proj: GEMM(att)+bias+BN + x residual -> x_attn f32 AND h1 spikes
    gemm_fused_kernel<<<gG, 256, 0, stream>>>(spkA, phi, plo, proj_b,
                                              proj_bn, sc_proj, nullptr, nullptr, nullptr, nullptr,
                                              x, x_attn, spkE, C_, C_, C_, 1);

    // fc1: GEMM+bias+BN+LIF -> h2 spikes
    gemm_fused_kernel<<<gGf1, 256, 0, stream>>>(spkE, f1hi, f1lo, fc1_b,
                                                fc1_bn, sc_fc1, nullptr, nullptr, nullptr, nullptr,
                                                nullptr, nullptr, h2, C_, HID_, HID_, 0);

    // fc2: GEMM+bias+BN + x_attn residual -> out1 (in place over x_attn)
    gemm_fused_kernel<<<gG, 256, 0, stream>>>(h2, f2hi, f2lo, fc2_b,
                                              fc2_bn, sc_fc2, nullptr, nullptr, nullptr, nullptr,
                                              x_attn, out1, nullptr, HID_, C_, C_, 2);
}

// Round 5
// 428.974 us; speedup vs baseline: 1.0550x; 1.0550x over previous
//
#include <hip/hip_runtime.h>
#include <stdint.h>

#pragma clang fp contract(off)

typedef _Float16 f16x8 __attribute__((ext_vector_type(8)));
typedef float f32x4 __attribute__((ext_vector_type(4)));
typedef unsigned short u16;
typedef u16 u16x8 __attribute__((ext_vector_type(8)));

#define T_   4
#define B_   16
#define C_   512
#define HID_ 2048
#define NPIX 256
#define Z_   64            // T_*B_

// ---------------- workspace layout (bytes) ----------------
constexpr size_t OFF_SC      = 0;                      // 6 slots x 8KB (q,k,v,proj,fc1,fc2)
constexpr size_t OFF_PRESUM  = 65536;                  // 4*64*512 i32 = 512KB
constexpr size_t OFF_MASK    = OFF_PRESUM + 524288;    // 64*512 u16 = 64KB
constexpr size_t OFF_W       = OFF_MASK + 65536;
constexpr size_t WSZ_S       = 524288;                 // 512*512*2
constexpr size_t WSZ_QKV     = 1572864;                // 1536*512*2
constexpr size_t WSZ_L       = 2097152;                // 2048*512*2
constexpr size_t OFF_QKVHI = OFF_W;
constexpr size_t OFF_QKVLO = OFF_QKVHI + WSZ_QKV;
constexpr size_t OFF_PHI   = OFF_QKVLO + WSZ_QKV;
constexpr size_t OFF_PLO   = OFF_PHI + WSZ_S;
constexpr size_t OFF_F1HI  = OFF_PLO + WSZ_S;
constexpr size_t OFF_F1LO  = OFF_F1HI + WSZ_L;
constexpr size_t OFF_F2HI  = OFF_F1LO + WSZ_L;
constexpr size_t OFF_F2LO  = OFF_F2HI + WSZ_L;
constexpr size_t OFF_SPK   = OFF_F2LO + WSZ_L;
constexpr size_t SPKB      = 16777216;                 // 64*256*512*2
constexpr size_t OFF_SPK_A   = OFF_SPK;                // xs -> att
constexpr size_t OFF_SPK_QKV = OFF_SPK + SPKB;         // [z][n][1536] (3*SPKB)
constexpr size_t OFF_SPK_E   = OFF_SPK + 4*SPKB;       // h1
constexpr size_t OFF_H2      = OFF_SPK + 5*SPKB;       // h2 (4*SPKB)

// ---------------- fused prep: BN scales, 6 segments ----------------
__global__ void prep_sc_all_kernel(const float* __restrict__ q_bn, const float* __restrict__ k_bn,
                                   const float* __restrict__ v_bn, const float* __restrict__ p_bn,
                                   const float* __restrict__ f1_bn, const float* __restrict__ f2_bn,
                                   float* __restrict__ scbase) {
    int i = blockIdx.x * 256 + threadIdx.x;   // 0..4607
    const float* bn; float* sc; int c; int Cn;
    if (i < 512)       { bn = q_bn;  sc = scbase;          c = i;        Cn = 512; }
    else if (i < 1024) { bn = k_bn;  sc = scbase + 2048;   c = i - 512;  Cn = 512; }
    else if (i < 1536) { bn = v_bn;  sc = scbase + 4096;   c = i - 1024; Cn = 512; }
    else if (i < 2048) { bn = p_bn;  sc = scbase + 6144;   c = i - 1536; Cn = 512; }
    else if (i < 4096) { bn = f1_bn; sc = scbase + 8192;   c = i - 2048; Cn = 2048; }
    else if (i < 4608) { bn = f2_bn; sc = scbase + 10240;  c = i - 4096; Cn = 512; }
    else return;
    sc[c] = bn[c] / sqrtf(bn[3 * Cn + c] + 1e-5f);
}

// ---------------- fused prep: f16 2-split of all weights ----------------
__global__ void prep_split_all_kernel(const float* __restrict__ q_w, const float* __restrict__ k_w,
                                      const float* __restrict__ v_w, const float* __restrict__ p_w,
                                      const float* __restrict__ f1_w, const float* __restrict__ f2_w,
                                      char* ws) {
    int i = blockIdx.x * 256 + threadIdx.x;   // 0..3145727
    const float* src; u16* hi; u16* lo; int j;
    u16* qkvhi = (u16*)(ws + OFF_QKVHI); u16* qkvlo = (u16*)(ws + OFF_QKVLO);
    if (i < 262144)        { src = q_w;  hi = qkvhi;           lo = qkvlo;           j = i; }
    else if (i < 524288)   { src = k_w;  hi = qkvhi + 262144;  lo = qkvlo + 262144;  j = i - 262144; }
    else if (i < 786432)   { src = v_w;  hi = qkvhi + 524288;  lo = qkvlo + 524288;  j = i - 524288; }
    else if (i < 1048576)  { src = p_w;  hi = (u16*)(ws + OFF_PHI);  lo = (u16*)(ws + OFF_PLO);  j = i - 786432; }
    else if (i < 2097152)  { src = f1_w; hi = (u16*)(ws + OFF_F1HI); lo = (u16*)(ws + OFF_F1LO); j = i - 1048576; }
    else if (i < 3145728)  { src = f2_w; hi = (u16*)(ws + OFF_F2HI); lo = (u16*)(ws + OFF_F2LO); j = i - 2097152; }
    else return;
    float w = src[j];
    _Float16 h = (_Float16)w;
    float d = w - (float)h;               // exact
    _Float16 l = (_Float16)(d * 2048.0f); // keep lo in f16 normal range
    hi[j] = *(const u16*)&h;
    lo[j] = *(const u16*)&l;
}

// ---------------- LIF + transpose: y[T,B,Cf,N] f32 -> spk[z][n][c] f16 ----------------
__global__ __launch_bounds__(256) void lif_transpose_kernel(
        const float* __restrict__ y, u16* __restrict__ spk, int Cf) {
    __shared__ __align__(16) u16 tile[256 * 72];   // [t*64+nn][72]
    int b  = blockIdx.z;
    int c0 = blockIdx.y * 64;
    int n0 = blockIdx.x * 64;
    int tid = threadIdx.x;
    int nn = tid & 63;
    int cg = tid >> 6;
    size_t tstride = (size_t)B_ * Cf * NPIX;
    for (int e = 0; e < 16; ++e) {
        int ci = cg * 16 + e;
        size_t base = ((size_t)b * Cf + c0 + ci) * NPIX + n0 + nn;
        float v = 0.0f;
        #pragma unroll
        for (int t = 0; t < T_; ++t) {
            float x = y[base + (size_t)t * tstride];
            v = v + (x - v) * 0.5f;
            u16 s = 0;
            if (v >= 1.0f) { s = 0x3C00; v = 0.0f; }
            tile[(t * 64 + nn) * 72 + ci] = s;
        }
    }
    __syncthreads();
    int t = tid >> 6, n2 = tid & 63;
    const u16* srow = &tile[(t * 64 + n2) * 72];
    u16* drow = spk + ((size_t)((t * B_ + b) * NPIX) + n0 + n2) * Cf + c0;
    #pragma unroll
    for (int kk = 0; kk < 8; ++kk)
        *(u16x8*)(drow + kk * 8) = *(const u16x8*)(srow + kk * 8);
}

// ---------------- kv presum (256 blocks): integer counts of (k&v) over n-quarter ----------------
__global__ void kv_presum_kernel(const u16* __restrict__ qkv, int* __restrict__ presum4) {
    int z  = blockIdx.x >> 2;
    int nq = blockIdx.x & 3;
    int tid = threadIdx.x;
    const uint* base = (const uint*)(qkv + (size_t)z * NPIX * 1536) + (size_t)nq * 64 * 768;
    int s0 = 0, s1 = 0;
    for (int n = 0; n < 64; ++n) {
        uint a = base[n * 768 + 256 + tid];   // k cols 512..1023
        uint b = base[n * 768 + 512 + tid];   // v cols 1024..1535
        uint c = a & b;
        s0 += (c >> 10) & 1;
        s1 += (c >> 26) & 1;
    }
    presum4[((nq * Z_ + z) << 9) + 2 * tid]     = s0;
    presum4[((nq * Z_ + z) << 9) + 2 * tid + 1] = s1;
}

// ---------------- kv LIF (vth=0.5) -> mask u16 ----------------
__global__ void kv_lif_mask_kernel(const int* __restrict__ presum4, u16* __restrict__ mask) {
    int i = blockIdx.x * 256 + threadIdx.x;   // 8192 = B_*C_
    int b = i >> 9, c = i & (C_ - 1);
    float v = 0.0f;
    #pragma unroll
    for (int t = 0; t < T_; ++t) {
        int z = t * B_ + b;
        int s = presum4[(z << 9) + c] + presum4[((Z_ + z) << 9) + c]
              + presum4[((2 * Z_ + z) << 9) + c] + presum4[((3 * Z_ + z) << 9) + c];
        float x = (float)s;                   // exact integer <= 256
        v = v + (x - v) * 0.5f;
        u16 m = 0;
        if (v >= 0.5f) { m = 0xFFFF; v = 0.0f; }
        mask[(z << 9) + c] = m;
    }
}

// ---------------- att = q & mask (q strided 1536, out compact 512) ----------------
__global__ void att_apply_kernel(const u16* __restrict__ qkv, const u16* __restrict__ mask,
                                 u16* __restrict__ att) {
    size_t i = (size_t)blockIdx.x * 256 + threadIdx.x;  // over 64*256*128 uint2-groups
    int z   = (int)(i >> 15);
    int rem = (int)(i & 32767);
    int n   = rem >> 7;
    int c4  = rem & 127;
    uint2 qv = ((const uint2*)qkv)[((size_t)z * NPIX + n) * 384 + c4];  // q at cols 0..511
    uint2 mv = ((const uint2*)(mask + (size_t)z * C_))[c4];
    uint2 r;
    r.x = qv.x & mv.x;
    r.y = qv.y & mv.y;
    ((uint2*)att)[i] = r;
}

// ---------------- vh output: out2[(z*8+h)][n][ch] = v[z][n][1024+h*64+ch] as f32 ----------------
__global__ void vh_write_kernel(const u16* __restrict__ qkv, float* __restrict__ out2) {
    int slab = blockIdx.x;           // z*8+h
    int z = slab >> 3, h = slab & 7;
    int tid = threadIdx.x;
    int n = tid >> 2, cg = tid & 3;
    for (int it = 0; it < 4; ++it) {
        int nn = n + it * 64;
        const u16* src = qkv + ((size_t)z * NPIX + nn) * 1536 + 1024 + h * 64 + cg * 16;
        float* dst = out2 + ((size_t)slab * NPIX + nn) * 64 + cg * 16;
        #pragma unroll
        for (int j = 0; j < 16; ++j) dst[j] = src[j] ? 1.0f : 0.0f;
    }
}

// ---------------- fused MFMA GEMM, dbuf BK=32, 64o x 32p x 4z, BN/LIF fused ----------------
// Sections: if bnp2/bnp3 non-null, o in [512,1024) uses bnp2/sc2, [1024,1536) uses bnp3/sc3.
// mode 0: spikes only; 1: f32 y(+res) AND spikes; 2: f32(+res) only.
__global__ __launch_bounds__(256, 4) void gemm_fused_kernel(
        const u16* __restrict__ S,     // [64][256][Cin] f16 spikes
        const u16* __restrict__ Whi,   // [Cout][Cin]
        const u16* __restrict__ Wlo,
        const float* __restrict__ bias,
        const float* __restrict__ bnp,  const float* __restrict__ sc,
        const float* __restrict__ bnp2, const float* __restrict__ sc2,
        const float* __restrict__ bnp3, const float* __restrict__ sc3,
        const float* res,              // [z][Cout][256] or null (may alias yout)
        float* yout,                   // [z][Cout][256] (modes 1,2)
        u16* spkout,                   // [z][n][Cout]   (modes 0,1)
        int Cin, int Cout, int Cn, int mode) {
    __shared__ __align__(16) char lds[32768];   // 2 stages x (Ahi 4K | Alo 4K | B 8K)
    float* ldsf = (float*)lds;
    const int tid  = threadIdx.x;
    const int lane = tid & 63;
    const int w    = tid >> 6;           // wave index = timestep t
    const int r15 = lane & 15, quad = lane >> 4;
    const int b  = blockIdx.z;
    const int o0 = blockIdx.y * 64;
    const int p0 = blockIdx.x * 32;
    const int zt = w * B_ + b;

    f32x4 acc1[4][2], acc2[4][2];
    #pragma unroll
    for (int a = 0; a < 4; ++a)
        #pragma unroll
        for (int c = 0; c < 2; ++c) {
            acc1[a][c] = (f32x4){0.f, 0.f, 0.f, 0.f};
            acc2[a][c] = (f32x4){0.f, 0.f, 0.f, 0.f};
        }

    const int srow = lane >> 2;   // staging row within 16-row group (0..15)
    const int sj   = lane & 3;    // staging 16B chunk slot (0..3)

    // stage one BK=32 slab (16KB) into buffer st
    auto stage = [&](int k0, int st) {
        #pragma unroll
        for (int e = 0; e < 4; ++e) {
            int g = w * 4 + e;              // 0..15
            const u16* src;
            int dstoff;
            if (g < 4) {                    // Ahi: 64 rows
                int m = g * 16 + srow;
                src = Whi + (size_t)(o0 + m) * Cin + k0 + ((sj ^ ((m >> 1) & 3)) << 3);
                dstoff = g * 1024;
            } else if (g < 8) {             // Alo
                int m = (g - 4) * 16 + srow;
                src = Wlo + (size_t)(o0 + m) * Cin + k0 + ((sj ^ ((m >> 1) & 3)) << 3);
                dstoff = 4096 + (g - 4) * 1024;
            } else {                        // B: 128 rows = 4z x 32p
                int r = (g - 8) * 16 + srow;
                int t = r >> 5, p = r & 31;
                src = S + ((size_t)((t * B_ + b) * NPIX + p0 + p)) * Cin + k0
                      + ((sj ^ ((r >> 1) & 3)) << 3);
                dstoff = 8192 + (g - 8) * 1024;
            }
            char* dst = lds + st * 16384 + dstoff;
            __builtin_amdgcn_global_load_lds(
                (const __attribute__((address_space(1))) void*)(uintptr_t)(const void*)src,
                (__attribute__((address_space(3))) void*)(uintptr_t)(void*)dst,
                16, 0, 0);
        }
    };

    const int nIter = Cin >> 5;
    stage(0, 0);
    for (int i = 0; i < nIter; ++i) {
        __syncthreads();                     // drains stage(i); compute(i-1) done
        if (i + 1 < nIter) stage((i + 1) << 5, (i + 1) & 1);
        const char* base = lds + (i & 1) * 16384;
        f16x8 af[4], al[4], bf[2];
        #pragma unroll
        for (int mt = 0; mt < 4; ++mt) {
            int m = mt * 16 + r15;
            int ad = m * 64 + ((quad ^ ((m >> 1) & 3)) << 4);
            af[mt] = *(const f16x8*)(base + ad);
            al[mt] = *(const f16x8*)(base + 4096 + ad);
        }
        #pragma unroll
        for (int nt = 0; nt < 2; ++nt) {
            int r = w * 32 + nt * 16 + r15;
            int ad = r * 64 + ((quad ^ ((r >> 1) & 3)) << 4);
            bf[nt] = *(const f16x8*)(base + 8192 + ad);
        }
        #pragma unroll
        for (int mt = 0; mt < 4; ++mt)
            #pragma unroll
            for (int nt = 0; nt < 2; ++nt) {
                acc1[mt][nt] = __builtin_amdgcn_mfma_f32_16x16x32_f16(af[mt], bf[nt], acc1[mt][nt], 0, 0, 0);
                acc2[mt][nt] = __builtin_amdgcn_mfma_f32_16x16x32_f16(al[mt], bf[nt], acc2[mt][nt], 0, 0, 0);
            }
    }

    // section-select BN params (qkv fused case)
    const float* bnpS = bnp;
    const float* scS  = sc;
    int ol0 = o0;
    if (bnp3 && o0 >= 1024)      { bnpS = bnp3; scS = sc3; ol0 = o0 - 1024; }
    else if (bnp2 && o0 >= 512)  { bnpS = bnp2; scS = sc2; ol0 = o0 - 512; }

    // combine splits + bias + BN (+res)
    f32x4 yv[4][2];
    const float inv2048 = 1.0f / 2048.0f;
    #pragma unroll
    for (int mt = 0; mt < 4; ++mt) {
        int obl = ol0 + mt * 16 + quad * 4;
        float scv[4], mm[4], bb[4], bv[4];
        #pragma unroll
        for (int r = 0; r < 4; ++r) {
            int o = obl + r;
            scv[r] = scS[o];
            mm[r]  = bnpS[2 * Cn + o];
            bb[r]  = bnpS[Cn + o];
            bv[r]  = bias ? bias[o] : 0.0f;
        }
        #pragma unroll
        for (int nt = 0; nt < 2; ++nt) {
            int p = p0 + nt * 16 + r15;
            #pragma unroll
            for (int r = 0; r < 4; ++r) {
                float y = acc1[mt][nt][r] + acc2[mt][nt][r] * inv2048 + bv[r];
                float val = (y - mm[r]) * scv[r] + bb[r];
                if (mode != 0) {
                    size_t idx = ((size_t)zt * Cout + o0 + mt * 16 + quad * 4 + r) * NPIX + p;
                    val += res[idx];
                }
                yv[mt][nt][r] = val;
            }
        }
    }
    if (mode != 0) {
        #pragma unroll
        for (int mt = 0; mt < 4; ++mt) {
            int ob = o0 + mt * 16 + quad * 4;
            #pragma unroll
            for (int nt = 0; nt < 2; ++nt) {
                int p = p0 + nt * 16 + r15;
                #pragma unroll
                for (int r = 0; r < 4; ++r)
                    yout[((size_t)zt * Cout + ob + r) * NPIX + p] = yv[mt][nt][r];
            }
        }
    }
    if (mode != 2) {
        // LIF across the 4 waves' timesteps via LDS, two 16-pixel phases
        __syncthreads();
        const int o2 = tid & 63, pj = tid >> 6;   // o2: out-channel, pj: p-group (0..3)
        #pragma unroll
        for (int ph = 0; ph < 2; ++ph) {
            #pragma unroll
            for (int mt = 0; mt < 4; ++mt) {
                int ol = mt * 16 + quad * 4;
                #pragma unroll
                for (int r = 0; r < 4; ++r)
                    ldsf[w * 1088 + (ol + r) * 17 + r15] = yv[mt][ph][r];
            }
            __syncthreads();
            u16 sp[4][4];
            #pragma unroll
            for (int jj = 0; jj < 4; ++jj) {
                int p = pj * 4 + jj;
                float v = 0.0f;
                #pragma unroll
                for (int t = 0; t < T_; ++t) {
                    float x = ldsf[t * 1088 + o2 * 17 + p];
                    v = v + (x - v) * 0.5f;
                    u16 s = 0;
                    if (v >= 1.0f) { s = 0x3C00; v = 0.0f; }
                    sp[t][jj] = s;
                }
            }
            #pragma unroll
            for (int t = 0; t < T_; ++t)
                #pragma unroll
                for (int jj = 0; jj < 4; ++jj)
                    spkout[((size_t)((t * B_ + b) * NPIX + p0 + ph * 16 + pj * 4 + jj)) * Cout
                           + o0 + o2] = sp[t][jj];
            __syncthreads();
        }
    }
}

extern "C" void kernel_launch(void* const* d_in, const int* in_sizes, int n_in,
                              void* d_out, int out_size, void* d_ws, size_t ws_size,
                              hipStream_t stream) {
    (void)in_sizes; (void)n_in; (void)out_size; (void)ws_size;
    const float* x       = (const float*)d_in[0];
    const float* q_w     = (const float*)d_in[1];
    const float* k_w     = (const float*)d_in[2];
    const float* v_w     = (const float*)d_in[3];
    const float* proj_w  = (const float*)d_in[4];
    const float* proj_b  = (const float*)d_in[5];
    const float* fc1_w   = (const float*)d_in[6];
    const float* fc1_b   = (const float*)d_in[7];
    const float* fc2_w   = (const float*)d_in[8];
    const float* fc2_b   = (const float*)d_in[9];
    const float* q_bn    = (const float*)d_in[10];
    const float* k_bn    = (const float*)d_in[11];
    const float* v_bn    = (const float*)d_in[12];
    const float* proj_bn = (const float*)d_in[13];
    const float* fc1_bn  = (const float*)d_in[14];
    const float* fc2_bn  = (const float*)d_in[15];

    char* ws = (char*)d_ws;
    float* scb     = (float*)(ws + OFF_SC);
    float* sc_q    = scb;
    float* sc_k    = scb + 2048;
    float* sc_v    = scb + 4096;
    float* sc_proj = scb + 6144;
    float* sc_fc1  = scb + 8192;
    float* sc_fc2  = scb + 10240;
    int*   presum4 = (int*)(ws + OFF_PRESUM);
    u16*   maskp   = (u16*)(ws + OFF_MASK);
    u16 *qkvhi = (u16*)(ws + OFF_QKVHI), *qkvlo = (u16*)(ws + OFF_QKVLO);
    u16 *phi = (u16*)(ws + OFF_PHI), *plo = (u16*)(ws + OFF_PLO);
    u16 *f1hi = (u16*)(ws + OFF_F1HI), *f1lo = (u16*)(ws + OFF_F1LO);
    u16 *f2hi = (u16*)(ws + OFF_F2HI), *f2lo = (u16*)(ws + OFF_F2LO);
    u16* spkA   = (u16*)(ws + OFF_SPK_A);    // xs -> att
    u16* spkQKV = (u16*)(ws + OFF_SPK_QKV);  // [z][n][1536]
    u16* spkE   = (u16*)(ws + OFF_SPK_E);    // h1
    u16* h2     = (u16*)(ws + OFF_H2);       // h2 (67MB)

    float* out1 = (float*)d_out;
    float* out2 = out1 + 8388608;
    float* x_attn = out1;                 // x_attn lives in out1 until fc2 overwrites in-place

    // fused prep (2 launches)
    prep_sc_all_kernel<<<18, 256, 0, stream>>>(q_bn, k_bn, v_bn, proj_bn, fc1_bn, fc2_bn, scb);
    prep_split_all_kernel<<<12288, 256, 0, stream>>>(q_w, k_w, v_w, proj_w, fc1_w, fc2_w, ws);

    dim3 gLT(4, 8, 16);       // lif_transpose on x (Cf=512)
    dim3 gQKV(8, 24, 16);     // fused gemm, Cout=1536: 3072 blocks
    dim3 gG(8, 8, 16);        // fused gemm, Cout=512: 1024 blocks
    dim3 gGf1(8, 32, 16);     // fused gemm, Cout=2048: 4096 blocks

    // shortcut LIF on x -> xs spikes [z][n][c]
    lif_transpose_kernel<<<gLT, 256, 0, stream>>>(x, spkA, C_);

    // q+k+v fused: GEMM+BN+LIF -> spikes [z][n][1536]
    gemm_fused_kernel<<<gQKV, 256, 0, stream>>>(spkA, qkvhi, qkvlo, nullptr,
                                                q_bn, sc_q, k_bn, sc_k, v_bn, sc_v,
                                                nullptr, nullptr, spkQKV, C_, 1536, C_, 0);

    // vh output + kv reduce + talking-heads LIF + att mask
    vh_write_kernel<<<512, 256, 0, stream>>>(spkQKV, out2);
    kv_presum_kernel<<<256, 256, 0, stream>>>(spkQKV, presum4);
    kv_lif_mask_kernel<<<32, 256, 0, stream>>>(presum4, maskp);
    att_apply_kernel<<<8192, 256, 0, stream>>>(spkQKV, maskp, spkA);   // att into A (xs dead)

    // proj: GEMM(att)+bias+BN + x residual -> x_attn f32 AND h1 spikes
    gemm_fused_kernel<<<gG, 256, 0, stream>>>(spkA, phi, plo, proj_b,
                                              proj_bn, sc_proj, nullptr, nullptr, nullptr, nullptr,
                                              x, x_attn, spkE, C_, C_, C_, 1);

    // fc1: GEMM+bias+BN+LIF -> h2 spikes
    gemm_fused_kernel<<<gGf1, 256, 0, stream>>>(spkE, f1hi, f1lo, fc1_b,
                                                fc1_bn, sc_fc1, nullptr, nullptr, nullptr, nullptr,
                                                nullptr, nullptr, h2, C_, HID_, HID_, 0);

    // fc2: GEMM+bias+BN + x_attn residual -> out1 (in place over x_attn)
    gemm_fused_kernel<<<gG, 256, 0, stream>>>(h2, f2hi, f2lo, fc2_b,
                                              fc2_bn, sc_fc2, nullptr, nullptr, nullptr, nullptr,
                                              x_attn, out1, nullptr, HID_, C_, C_, 2);
}

// Round 6
// 411.276 us; speedup vs baseline: 1.1004x; 1.0430x over previous
//
#include <hip/hip_runtime.h>
#include <stdint.h>

#pragma clang fp contract(off)

typedef _Float16 f16x8 __attribute__((ext_vector_type(8)));
typedef float f32x4 __attribute__((ext_vector_type(4)));
typedef unsigned short u16;
typedef u16 u16x8 __attribute__((ext_vector_type(8)));

#define T_   4
#define B_   16
#define C_   512
#define HID_ 2048
#define NPIX 256
#define Z_   64            // T_*B_

// ---------------- workspace layout (bytes) ----------------
constexpr size_t OFF_SC      = 0;                      // 6 slots x 8KB (q,k,v,proj,fc1,fc2)
constexpr size_t OFF_PRESUM  = 65536;                  // 4*64*512 i32 = 512KB
constexpr size_t OFF_MASK    = OFF_PRESUM + 524288;    // 64*512 u16 = 64KB
constexpr size_t OFF_W       = OFF_MASK + 65536;
constexpr size_t WSZ_S       = 524288;                 // 512*512*2
constexpr size_t WSZ_QKV     = 1572864;                // 1536*512*2
constexpr size_t WSZ_L       = 2097152;                // 2048*512*2
constexpr size_t OFF_QKVHI = OFF_W;
constexpr size_t OFF_QKVLO = OFF_QKVHI + WSZ_QKV;
constexpr size_t OFF_PHI   = OFF_QKVLO + WSZ_QKV;
constexpr size_t OFF_PLO   = OFF_PHI + WSZ_S;
constexpr size_t OFF_F1HI  = OFF_PLO + WSZ_S;
constexpr size_t OFF_F1LO  = OFF_F1HI + WSZ_L;
constexpr size_t OFF_F2HI  = OFF_F1LO + WSZ_L;
constexpr size_t OFF_F2LO  = OFF_F2HI + WSZ_L;
constexpr size_t OFF_SPK   = OFF_F2LO + WSZ_L;
constexpr size_t SPKB      = 16777216;                 // 64*256*512*2
constexpr size_t OFF_SPK_A   = OFF_SPK;                // xs -> att
constexpr size_t OFF_SPK_QKV = OFF_SPK + SPKB;         // [z][n][1536] (3*SPKB)
constexpr size_t OFF_SPK_E   = OFF_SPK + 4*SPKB;       // h1
constexpr size_t OFF_H2      = OFF_SPK + 5*SPKB;       // h2 (4*SPKB)

// ---------------- fused prep: BN scales, 6 segments ----------------
__global__ void prep_sc_all_kernel(const float* __restrict__ q_bn, const float* __restrict__ k_bn,
                                   const float* __restrict__ v_bn, const float* __restrict__ p_bn,
                                   const float* __restrict__ f1_bn, const float* __restrict__ f2_bn,
                                   float* __restrict__ scbase) {
    int i = blockIdx.x * 256 + threadIdx.x;   // 0..4607
    const float* bn; float* sc; int c; int Cn;
    if (i < 512)       { bn = q_bn;  sc = scbase;          c = i;        Cn = 512; }
    else if (i < 1024) { bn = k_bn;  sc = scbase + 2048;   c = i - 512;  Cn = 512; }
    else if (i < 1536) { bn = v_bn;  sc = scbase + 4096;   c = i - 1024; Cn = 512; }
    else if (i < 2048) { bn = p_bn;  sc = scbase + 6144;   c = i - 1536; Cn = 512; }
    else if (i < 4096) { bn = f1_bn; sc = scbase + 8192;   c = i - 2048; Cn = 2048; }
    else if (i < 4608) { bn = f2_bn; sc = scbase + 10240;  c = i - 4096; Cn = 512; }
    else return;
    sc[c] = bn[c] / sqrtf(bn[3 * Cn + c] + 1e-5f);
}

// ---------------- fused prep: f16 2-split of all weights ----------------
__global__ void prep_split_all_kernel(const float* __restrict__ q_w, const float* __restrict__ k_w,
                                      const float* __restrict__ v_w, const float* __restrict__ p_w,
                                      const float* __restrict__ f1_w, const float* __restrict__ f2_w,
                                      char* ws) {
    int i = blockIdx.x * 256 + threadIdx.x;   // 0..3145727
    const float* src; u16* hi; u16* lo; int j;
    u16* qkvhi = (u16*)(ws + OFF_QKVHI); u16* qkvlo = (u16*)(ws + OFF_QKVLO);
    if (i < 262144)        { src = q_w;  hi = qkvhi;           lo = qkvlo;           j = i; }
    else if (i < 524288)   { src = k_w;  hi = qkvhi + 262144;  lo = qkvlo + 262144;  j = i - 262144; }
    else if (i < 786432)   { src = v_w;  hi = qkvhi + 524288;  lo = qkvlo + 524288;  j = i - 524288; }
    else if (i < 1048576)  { src = p_w;  hi = (u16*)(ws + OFF_PHI);  lo = (u16*)(ws + OFF_PLO);  j = i - 786432; }
    else if (i < 2097152)  { src = f1_w; hi = (u16*)(ws + OFF_F1HI); lo = (u16*)(ws + OFF_F1LO); j = i - 1048576; }
    else if (i < 3145728)  { src = f2_w; hi = (u16*)(ws + OFF_F2HI); lo = (u16*)(ws + OFF_F2LO); j = i - 2097152; }
    else return;
    float w = src[j];
    _Float16 h = (_Float16)w;
    float d = w - (float)h;               // exact
    _Float16 l = (_Float16)(d * 2048.0f); // keep lo in f16 normal range
    hi[j] = *(const u16*)&h;
    lo[j] = *(const u16*)&l;
}

// ---------------- LIF + transpose: y[T,B,Cf,N] f32 -> spk[z][n][c] f16 ----------------
__global__ __launch_bounds__(256) void lif_transpose_kernel(
        const float* __restrict__ y, u16* __restrict__ spk, int Cf) {
    __shared__ __align__(16) u16 tile[256 * 72];   // [t*64+nn][72]
    int b  = blockIdx.z;
    int c0 = blockIdx.y * 64;
    int n0 = blockIdx.x * 64;
    int tid = threadIdx.x;
    int nn = tid & 63;
    int cg = tid >> 6;
    size_t tstride = (size_t)B_ * Cf * NPIX;
    for (int e = 0; e < 16; ++e) {
        int ci = cg * 16 + e;
        size_t base = ((size_t)b * Cf + c0 + ci) * NPIX + n0 + nn;
        float v = 0.0f;
        #pragma unroll
        for (int t = 0; t < T_; ++t) {
            float x = y[base + (size_t)t * tstride];
            v = v + (x - v) * 0.5f;
            u16 s = 0;
            if (v >= 1.0f) { s = 0x3C00; v = 0.0f; }
            tile[(t * 64 + nn) * 72 + ci] = s;
        }
    }
    __syncthreads();
    int t = tid >> 6, n2 = tid & 63;
    const u16* srow = &tile[(t * 64 + n2) * 72];
    u16* drow = spk + ((size_t)((t * B_ + b) * NPIX) + n0 + n2) * Cf + c0;
    #pragma unroll
    for (int kk = 0; kk < 8; ++kk)
        *(u16x8*)(drow + kk * 8) = *(const u16x8*)(srow + kk * 8);
}

// ---------------- kv presum (256 blocks): integer counts of (k&v) over n-quarter ----------------
__global__ void kv_presum_kernel(const u16* __restrict__ qkv, int* __restrict__ presum4) {
    int z  = blockIdx.x >> 2;
    int nq = blockIdx.x & 3;
    int tid = threadIdx.x;
    const uint* base = (const uint*)(qkv + (size_t)z * NPIX * 1536) + (size_t)nq * 64 * 768;
    int s0 = 0, s1 = 0;
    for (int n = 0; n < 64; ++n) {
        uint a = base[n * 768 + 256 + tid];   // k cols 512..1023
        uint b = base[n * 768 + 512 + tid];   // v cols 1024..1535
        uint c = a & b;
        s0 += (c >> 10) & 1;
        s1 += (c >> 26) & 1;
    }
    presum4[((nq * Z_ + z) << 9) + 2 * tid]     = s0;
    presum4[((nq * Z_ + z) << 9) + 2 * tid + 1] = s1;
}

// ---------------- kv LIF (vth=0.5) -> mask u16 ----------------
__global__ void kv_lif_mask_kernel(const int* __restrict__ presum4, u16* __restrict__ mask) {
    int i = blockIdx.x * 256 + threadIdx.x;   // 8192 = B_*C_
    int b = i >> 9, c = i & (C_ - 1);
    float v = 0.0f;
    #pragma unroll
    for (int t = 0; t < T_; ++t) {
        int z = t * B_ + b;
        int s = presum4[(z << 9) + c] + presum4[((Z_ + z) << 9) + c]
              + presum4[((2 * Z_ + z) << 9) + c] + presum4[((3 * Z_ + z) << 9) + c];
        float x = (float)s;                   // exact integer <= 256
        v = v + (x - v) * 0.5f;
        u16 m = 0;
        if (v >= 0.5f) { m = 0xFFFF; v = 0.0f; }
        mask[(z << 9) + c] = m;
    }
}

// ---------------- att = q & mask (q strided 1536, out compact 512) ----------------
__global__ void att_apply_kernel(const u16* __restrict__ qkv, const u16* __restrict__ mask,
                                 u16* __restrict__ att) {
    size_t i = (size_t)blockIdx.x * 256 + threadIdx.x;  // over 64*256*128 uint2-groups
    int z   = (int)(i >> 15);
    int rem = (int)(i & 32767);
    int n   = rem >> 7;
    int c4  = rem & 127;
    uint2 qv = ((const uint2*)qkv)[((size_t)z * NPIX + n) * 384 + c4];  // q at cols 0..511
    uint2 mv = ((const uint2*)(mask + (size_t)z * C_))[c4];
    uint2 r;
    r.x = qv.x & mv.x;
    r.y = qv.y & mv.y;
    ((uint2*)att)[i] = r;
}

// ---------------- fused MFMA GEMM, dbuf BK=32, 64o x 32p x 4z, BN/LIF fused ----------------
// 1-D grid, XCD-swizzled: id = px + 8*b + 128*oy  (id%8 = px -> same-B blocks share an XCD L2)
// Sections: if bnp2/bnp3 non-null, o in [512,1024) uses bnp2/sc2, [1024,1536) uses bnp3/sc3.
// mode 0: spikes only; 1: f32 y(+res) AND spikes; 2: f32(+res) only.
// vhout (qkv only): v-section spikes also stored as f32 [z][h][n][64].
__global__ __launch_bounds__(256, 4) void gemm_fused_kernel(
        const u16* __restrict__ S,     // [64][256][Cin] f16 spikes
        const u16* __restrict__ Whi,   // [Cout][Cin]
        const u16* __restrict__ Wlo,
        const float* __restrict__ bias,
        const float* __restrict__ bnp,  const float* __restrict__ sc,
        const float* __restrict__ bnp2, const float* __restrict__ sc2,
        const float* __restrict__ bnp3, const float* __restrict__ sc3,
        const float* res,              // [z][Cout][256] or null (may alias yout)
        float* yout,                   // [z][Cout][256] (modes 1,2)
        u16* spkout,                   // [z][n][Cout]   (modes 0,1)
        float* vhout,                  // vh f32 out or null
        int Cin, int Cout, int Cn, int mode) {
    __shared__ __align__(16) char lds[32768];   // 2 stages x (Ahi 4K | Alo 4K | B 8K)
    float* ldsf = (float*)lds;
    const int tid  = threadIdx.x;
    const int lane = tid & 63;
    const int w    = tid >> 6;           // wave index = timestep t
    const int r15 = lane & 15, quad = lane >> 4;
    const int id = blockIdx.x;
    const int b  = (id >> 3) & 15;
    const int o0 = (id >> 7) * 64;
    const int p0 = (id & 7) * 32;
    const int zt = w * B_ + b;

    f32x4 acc1[4][2], acc2[4][2];
    #pragma unroll
    for (int a = 0; a < 4; ++a)
        #pragma unroll
        for (int c = 0; c < 2; ++c) {
            acc1[a][c] = (f32x4){0.f, 0.f, 0.f, 0.f};
            acc2[a][c] = (f32x4){0.f, 0.f, 0.f, 0.f};
        }

    const int srow = lane >> 2;   // staging row within 16-row group (0..15)
    const int sj   = lane & 3;    // staging 16B chunk slot (0..3)

    // ---- hoisted staging sources (advance by +32 u16 per BK) ----
    const u16* ssrc[4];
    int sdst[4];
    #pragma unroll
    for (int e = 0; e < 4; ++e) {
        int g = w * 4 + e;              // 0..15 (wave-uniform branch)
        if (g < 4) {                    // Ahi: 64 rows
            int m = g * 16 + srow;
            ssrc[e] = Whi + (size_t)(o0 + m) * Cin + ((sj ^ ((m >> 1) & 3)) << 3);
            sdst[e] = g * 1024;
        } else if (g < 8) {             // Alo
            int m = (g - 4) * 16 + srow;
            ssrc[e] = Wlo + (size_t)(o0 + m) * Cin + ((sj ^ ((m >> 1) & 3)) << 3);
            sdst[e] = 4096 + (g - 4) * 1024;
        } else {                        // B: 128 rows = 4z x 32p
            int r = (g - 8) * 16 + srow;
            int t = r >> 5, p = r & 31;
            ssrc[e] = S + ((size_t)((t * B_ + b) * NPIX + p0 + p)) * Cin
                      + ((sj ^ ((r >> 1) & 3)) << 3);
            sdst[e] = 8192 + (g - 8) * 1024;
        }
    }

    auto stage = [&](int k0, int st) {
        #pragma unroll
        for (int e = 0; e < 4; ++e) {
            __builtin_amdgcn_global_load_lds(
                (const __attribute__((address_space(1))) void*)(uintptr_t)(const void*)(ssrc[e] + k0),
                (__attribute__((address_space(3))) void*)(uintptr_t)(void*)(lds + st * 16384 + sdst[e]),
                16, 0, 0);
        }
    };

    // ---- hoisted ds_read offsets ----
    int offA[4], offL[4], offB[2];
    #pragma unroll
    for (int mt = 0; mt < 4; ++mt) {
        int m = mt * 16 + r15;
        offA[mt] = m * 64 + ((quad ^ ((m >> 1) & 3)) << 4);
        offL[mt] = 4096 + offA[mt];
    }
    #pragma unroll
    for (int nt = 0; nt < 2; ++nt) {
        int r = w * 32 + nt * 16 + r15;
        offB[nt] = 8192 + r * 64 + ((quad ^ ((r >> 1) & 3)) << 4);
    }

    auto compute = [&](int bufbase) {
        f16x8 af[4], al[4], bf[2];
        #pragma unroll
        for (int mt = 0; mt < 4; ++mt) {
            af[mt] = *(const f16x8*)(lds + bufbase + offA[mt]);
            al[mt] = *(const f16x8*)(lds + bufbase + offL[mt]);
        }
        #pragma unroll
        for (int nt = 0; nt < 2; ++nt)
            bf[nt] = *(const f16x8*)(lds + bufbase + offB[nt]);
        #pragma unroll
        for (int mt = 0; mt < 4; ++mt)
            #pragma unroll
            for (int nt = 0; nt < 2; ++nt) {
                acc1[mt][nt] = __builtin_amdgcn_mfma_f32_16x16x32_f16(af[mt], bf[nt], acc1[mt][nt], 0, 0, 0);
                acc2[mt][nt] = __builtin_amdgcn_mfma_f32_16x16x32_f16(al[mt], bf[nt], acc2[mt][nt], 0, 0, 0);
            }
    };

    const int nIter = Cin >> 5;   // 16 or 32, always even
    stage(0, 0);
    int k = 32;
    for (int i = 0; i < nIter; i += 2) {
        __syncthreads();
        if (i + 1 < nIter) stage(k, 1);
        k += 32;
        compute(0);
        __syncthreads();
        if (i + 2 < nIter) stage(k, 0);
        k += 32;
        compute(16384);
    }

    // section-select BN params (qkv fused case)
    const float* bnpS = bnp;
    const float* scS  = sc;
    int ol0 = o0;
    if (bnp3 && o0 >= 1024)      { bnpS = bnp3; scS = sc3; ol0 = o0 - 1024; }
    else if (bnp2 && o0 >= 512)  { bnpS = bnp2; scS = sc2; ol0 = o0 - 512; }

    // combine splits + bias + BN (+res)
    f32x4 yv[4][2];
    const float inv2048 = 1.0f / 2048.0f;
    #pragma unroll
    for (int mt = 0; mt < 4; ++mt) {
        int obl = ol0 + mt * 16 + quad * 4;
        float scv[4], mm[4], bb[4], bv[4];
        #pragma unroll
        for (int r = 0; r < 4; ++r) {
            int o = obl + r;
            scv[r] = scS[o];
            mm[r]  = bnpS[2 * Cn + o];
            bb[r]  = bnpS[Cn + o];
            bv[r]  = bias ? bias[o] : 0.0f;
        }
        #pragma unroll
        for (int nt = 0; nt < 2; ++nt) {
            int p = p0 + nt * 16 + r15;
            #pragma unroll
            for (int r = 0; r < 4; ++r) {
                float y = acc1[mt][nt][r] + acc2[mt][nt][r] * inv2048 + bv[r];
                float val = (y - mm[r]) * scv[r] + bb[r];
                if (mode != 0) {
                    size_t idx = ((size_t)zt * Cout + o0 + mt * 16 + quad * 4 + r) * NPIX + p;
                    val += res[idx];
                }
                yv[mt][nt][r] = val;
            }
        }
    }
    if (mode != 0) {
        #pragma unroll
        for (int mt = 0; mt < 4; ++mt) {
            int ob = o0 + mt * 16 + quad * 4;
            #pragma unroll
            for (int nt = 0; nt < 2; ++nt) {
                int p = p0 + nt * 16 + r15;
                #pragma unroll
                for (int r = 0; r < 4; ++r)
                    yout[((size_t)zt * Cout + ob + r) * NPIX + p] = yv[mt][nt][r];
            }
        }
    }
    if (mode != 2) {
        // LIF across the 4 waves' timesteps via LDS, two 16-pixel phases
        __syncthreads();
        const int o2 = tid & 63, pj = tid >> 6;   // o2: out-channel, pj: p-group (0..3)
        const bool dovh = (vhout != nullptr) && (o0 >= 1024);
        const int hsec = (o0 - 1024) >> 6;
        #pragma unroll
        for (int ph = 0; ph < 2; ++ph) {
            #pragma unroll
            for (int mt = 0; mt < 4; ++mt) {
                int ol = mt * 16 + quad * 4;
                #pragma unroll
                for (int r = 0; r < 4; ++r)
                    ldsf[w * 1088 + (ol + r) * 17 + r15] = yv[mt][ph][r];
            }
            __syncthreads();
            u16 sp[4][4];
            #pragma unroll
            for (int jj = 0; jj < 4; ++jj) {
                int p = pj * 4 + jj;
                float v = 0.0f;
                #pragma unroll
                for (int t = 0; t < T_; ++t) {
                    float x = ldsf[t * 1088 + o2 * 17 + p];
                    v = v + (x - v) * 0.5f;
                    u16 s = 0;
                    if (v >= 1.0f) { s = 0x3C00; v = 0.0f; }
                    sp[t][jj] = s;
                }
            }
            #pragma unroll
            for (int t = 0; t < T_; ++t)
                #pragma unroll
                for (int jj = 0; jj < 4; ++jj) {
                    int p = p0 + ph * 16 + pj * 4 + jj;
                    spkout[((size_t)((t * B_ + b) * NPIX + p)) * Cout + o0 + o2] = sp[t][jj];
                    if (dovh)
                        vhout[((((size_t)(t * B_ + b)) * 8 + hsec) * NPIX + p) * 64 + o2] =
                            sp[t][jj] ? 1.0f : 0.0f;
                }
            __syncthreads();
        }
    }
}

extern "C" void kernel_launch(void* const* d_in, const int* in_sizes, int n_in,
                              void* d_out, int out_size, void* d_ws, size_t ws_size,
                              hipStream_t stream) {
    (void)in_sizes; (void)n_in; (void)out_size; (void)ws_size;
    const float* x       = (const float*)d_in[0];
    const float* q_w     = (const float*)d_in[1];
    const float* k_w     = (const float*)d_in[2];
    const float* v_w     = (const float*)d_in[3];
    const float* proj_w  = (const float*)d_in[4];
    const float* proj_b  = (const float*)d_in[5];
    const float* fc1_w   = (const float*)d_in[6];
    const float* fc1_b   = (const float*)d_in[7];
    const float* fc2_w   = (const float*)d_in[8];
    const float* fc2_b   = (const float*)d_in[9];
    const float* q_bn    = (const float*)d_in[10];
    const float* k_bn    = (const float*)d_in[11];
    const float* v_bn    = (const float*)d_in[12];
    const float* proj_bn = (const float*)d_in[13];
    const float* fc1_bn  = (const float*)d_in[14];
    const float* fc2_bn  = (const float*)d_in[15];

    char* ws = (char*)d_ws;
    float* scb     = (float*)(ws + OFF_SC);
    float* sc_q    = scb;
    float* sc_k    = scb + 2048;
    float* sc_v    = scb + 4096;
    float* sc_proj = scb + 6144;
    float* sc_fc1  = scb + 8192;
    float* sc_fc2  = scb + 10240;
    int*   presum4 = (int*)(ws + OFF_PRESUM);
    u16*   maskp   = (u16*)(ws + OFF_MASK);
    u16 *qkvhi = (u16*)(ws + OFF_QKVHI), *qkvlo = (u16*)(ws + OFF_QKVLO);
    u16 *phi = (u16*)(ws + OFF_PHI), *plo = (u16*)(ws + OFF_PLO);
    u16 *f1hi = (u16*)(ws + OFF_F1HI), *f1lo = (u16*)(ws + OFF_F1LO);
    u16 *f2hi = (u16*)(ws + OFF_F2HI), *f2lo = (u16*)(ws + OFF_F2LO);
    u16* spkA   = (u16*)(ws + OFF_SPK_A);    // xs -> att
    u16* spkQKV = (u16*)(ws + OFF_SPK_QKV);  // [z][n][1536]
    u16* spkE   = (u16*)(ws + OFF_SPK_E);    // h1
    u16* h2     = (u16*)(ws + OFF_H2);       // h2 (67MB)

    float* out1 = (float*)d_out;
    float* out2 = out1 + 8388608;
    float* x_attn = out1;                 // x_attn lives in out1 until fc2 overwrites in-place

    // fused prep (2 launches)
    prep_sc_all_kernel<<<18, 256, 0, stream>>>(q_bn, k_bn, v_bn, proj_bn, fc1_bn, fc2_bn, scb);
    prep_split_all_kernel<<<12288, 256, 0, stream>>>(q_w, k_w, v_w, proj_w, fc1_w, fc2_w, ws);

    dim3 gLT(4, 8, 16);       // lif_transpose on x (Cf=512)

    // shortcut LIF on x -> xs spikes [z][n][c]
    lif_transpose_kernel<<<gLT, 256, 0, stream>>>(x, spkA, C_);

    // q+k+v fused: GEMM+BN+LIF -> spikes [z][n][1536]; v-section also writes vh f32 (out2)
    gemm_fused_kernel<<<24 * 128, 256, 0, stream>>>(spkA, qkvhi, qkvlo, nullptr,
                                                q_bn, sc_q, k_bn, sc_k, v_bn, sc_v,
                                                nullptr, nullptr, spkQKV, out2, C_, 1536, C_, 0);

    // kv reduce + talking-heads LIF + att mask
    kv_presum_kernel<<<256, 256, 0, stream>>>(spkQKV, presum4);
    kv_lif_mask_kernel<<<32, 256, 0, stream>>>(presum4, maskp);
    att_apply_kernel<<<8192, 256, 0, stream>>>(spkQKV, maskp, spkA);   // att into A (xs dead)

    // proj: GEMM(att)+bias+BN + x residual -> x_attn f32 AND h1 spikes
    gemm_fused_kernel<<<8 * 128, 256, 0, stream>>>(spkA, phi, plo, proj_b,
                                              proj_bn, sc_proj, nullptr, nullptr, nullptr, nullptr,
                                              x, x_attn, spkE, nullptr, C_, C_, C_, 1);

    // fc1: GEMM+bias+BN+LIF -> h2 spikes
    gemm_fused_kernel<<<32 * 128, 256, 0, stream>>>(spkE, f1hi, f1lo, fc1_b,
                                                fc1_bn, sc_fc1, nullptr, nullptr, nullptr, nullptr,
                                                nullptr, nullptr, h2, nullptr, C_, HID_, HID_, 0);

    // fc2: GEMM+bias+BN + x_attn residual -> out1 (in place over x_attn)
    gemm_fused_kernel<<<8 * 128, 256, 0, stream>>>(h2, f2hi, f2lo, fc2_b,
                                              fc2_bn, sc_fc2, nullptr, nullptr, nullptr, nullptr,
                                              x_attn, out1, nullptr, nullptr, HID_, C_, C_, 2);
}